// Round 20
// baseline (5154.139 us; speedup 1.0000x reference)
//
#include <hip/hip_runtime.h>
#include <hip/hip_bf16.h>
#include <math.h>

// DiffusionFlow: fused 10-step flow + log-det on MI355X.
// Round 20 = r19 (4.95ms: 512 thr / 8 waves, wave owns 64 cols, 32x32x16
// intrinsic MFMA acc-in-AGPR, 1040B odd-stride LDS, folded W3 projection,
// minimal-live K-loop) + two trims:
//  (a) det/state folded into registers: every thread redundantly sums the 8
//      wave-partials for its sample (identical fp order -> deterministic),
//      z/log_det live in registers. Removes det phase, zbuf/ldbuf, and one
//      barrier per step (5 -> 4). part stride padded to 9 floats
//      (conflict-free writes: bank = (l31*9+j)%32, odd stride).
//  (b) A-prefetch depth-2 wrap-around (L2 latency ~200-400cyc > depth-1's
//      192cyc of MFMA cover). +8 arch regs -> ~120 <= the 128 cap r19
//      proved spill-free at 512 thr.

typedef float  f32x4  __attribute__((ext_vector_type(4)));
typedef float  f32x16 __attribute__((ext_vector_type(16)));
typedef __bf16 bf16x8 __attribute__((ext_vector_type(8)));

#define ROWB(r) (((r) << 10) + ((r) << 4))   // r * 1040

static __device__ __forceinline__ unsigned pkbf2(float a, float b) {
    unsigned short lo = __builtin_bit_cast(unsigned short, __float2bfloat16(a));
    unsigned short hi = __builtin_bit_cast(unsigned short, __float2bfloat16(b));
    return (unsigned)lo | ((unsigned)hi << 16);
}

// ---- pack W (512x512 row-major fp32) -> bf16 A-frag order for 32x32x16 ----
// out[(((c*16+nb)*64)+l)*8+j] = W[nb*32+(l&31)][c*16+(l>>5)*8+j]  (verified r5-r19)
__global__ void pack_w_kernel(const float* __restrict__ W,
                              __hip_bfloat16* __restrict__ out) {
    int i  = blockIdx.x * 512 + threadIdx.x;
    int c  = i >> 13;
    int nb = (i >> 9) & 15;
    int l  = (i >> 3) & 63;
    int j  = i & 7;
    int n  = nb * 32 + (l & 31);
    int k  = c * 16 + ((l >> 5) << 3) + j;
    out[i] = __float2bfloat16(W[n * 512 + k]);
}

// ---- pack W0 cols 0,1 -> contiguous [512][2] fp32 ----
__global__ void pack_w0_kernel(const float* __restrict__ W0,
                               float* __restrict__ w01) {
    int o = threadIdx.x;
    w01[o * 2 + 0] = W0[o * 34 + 0];
    w01[o * 2 + 1] = W0[o * 34 + 1];
}

// ---- c_step[k][o] = b0[o] + W0[o,2:34] . temb(t_k) ----
__global__ void cstep_kernel(const float* __restrict__ W0,
                             const float* __restrict__ b0,
                             float* __restrict__ cst) {
    int k = blockIdx.x;
    int o = threadIdx.x;
    float t = (float)k * 0.1f;
    float acc = b0[o];
    #pragma unroll
    for (int j = 0; j < 16; ++j) {
        float f   = expf(-9.210340371976184f * (float)j / 16.0f);
        float arg = t * f;
        acc += W0[o * 34 + 2 + j]  * sinf(arg);
        acc += W0[o * 34 + 18 + j] * cosf(arg);
    }
    cst[k * 512 + o] = acc;
}

__global__ __launch_bounds__(512)
void flow_kernel(const float* __restrict__ x,
                 const float* __restrict__ w01,
                 const float* __restrict__ cst,
                 const __hip_bfloat16* __restrict__ Wpk1,
                 const __hip_bfloat16* __restrict__ Wpk2,
                 const float* __restrict__ b1,
                 const float* __restrict__ b2,
                 const float* __restrict__ W3,
                 const float* __restrict__ b3v,
                 float* __restrict__ out)
{
    __shared__ __align__(16) char Xbuf[96 * 1040];           // 99.8 KB, odd stride
    __shared__ __align__(16) float part[8][32][9];           // 9-float stride: CF writes

    const int tid  = threadIdx.x;
    const int lane = tid & 63;
    const int wid  = tid >> 6;        // 0..7 -> cols [wid*64, wid*64+64)
    const int l31  = lane & 31;
    const int hi   = lane >> 5;       // 0/1
    const int n0w  = wid << 6;
    const int wgs  = blockIdx.x << 5; // 32 samples per WG

    // B-frag (X from LDS): rows l31 / 32+l31 / 64+l31, stride 1040
    const int rowb0 = ROWB(l31);
    const int rowb1 = ROWB(32 + l31);
    const int rowb2 = ROWB(64 + l31);
    const int hi16  = hi << 4;
    // A-frags: uint4 index = c*1024 + abase (+64 for 2nd n-tile)
    const int abase = (wid << 7) + lane;
    const uint4* Wp1 = (const uint4*)Wpk1;
    const uint4* Wp2 = (const uint4*)Wpk2;

    // L0 split: s0 = sample (tid>>4, 0..31), t16 = 16-way column split
    const int s0  = tid >> 4;
    const int t16 = tid & 15;

    // z / log_det in registers, redundant across the 16 threads of a sample
    float z0r = x[(wgs + s0) * 2 + 0];
    float z1r = x[(wgs + s0) * 2 + 1];
    float ldr = 0.0f;
    const float b3x = b3v[0];
    const float b3y = b3v[1];

    const char* xb = (const char*)Xbuf;

    #pragma unroll 1
    for (int step = 0; step < 10; ++step) {
        // ---------- layer 0: rank-2 + step-constant, 32 outs/thread ----------
        {
            const float* cs = cst + (step << 9);
            char* base0 = Xbuf + ROWB(s0);
            #pragma unroll 1
            for (int m = 0; m < 4; ++m) {
                int ob = (t16 << 5) + (m << 3);    // element base, 8 outs
                const float4* wv4 = (const float4*)(w01 + (ob << 1));
                const float4* cv4 = (const float4*)(cs + ob);
                unsigned ph[4], p0[4], p1[4];
                #pragma unroll
                for (int jj = 0; jj < 4; ++jj) {
                    float4 wv = wv4[jj];                    // pairs (x,y),(z,w)
                    float4 cv = cv4[jj >> 1];
                    float c0 = (jj & 1) ? cv.z : cv.x;
                    float c1 = (jj & 1) ? cv.w : cv.y;
                    float a0  = fmaf(z0r, wv.x, fmaf(z1r, wv.y, c0));
                    float sg0 = 1.0f / (1.0f + __expf(-a0));
                    float h0  = a0 * sg0;
                    float sp0 = fmaf(h0, 1.0f - sg0, sg0);  // silu'(a0)
                    float a1  = fmaf(z0r, wv.z, fmaf(z1r, wv.w, c1));
                    float sg1 = 1.0f / (1.0f + __expf(-a1));
                    float h1  = a1 * sg1;
                    float sp1 = fmaf(h1, 1.0f - sg1, sg1);
                    ph[jj] = pkbf2(h0, h1);
                    p0[jj] = pkbf2(sp0 * wv.x, sp1 * wv.z);
                    p1[jj] = pkbf2(sp0 * wv.y, sp1 * wv.w);
                }
                int off = ob << 1;
                uint4 vph = {ph[0], ph[1], ph[2], ph[3]};
                uint4 vp0 = {p0[0], p0[1], p0[2], p0[3]};
                uint4 vp1 = {p1[0], p1[1], p1[2], p1[3]};
                *(uint4*)(base0 + off)             = vph;
                *(uint4*)(base0 + ROWB(32) + off)  = vp0;
                *(uint4*)(base0 + ROWB(64) + off)  = vp1;
            }
        }
        __syncthreads();

        // ---------- layers 1,2: D = W @ X^T via 32x32x16 MFMA (intrinsic) ----------
        #pragma unroll 1
        for (int layer = 0; layer < 2; ++layer) {
            const uint4* __restrict__ Wp   = layer ? Wp2 : Wp1;
            const float* __restrict__ bias = layer ? b2  : b1;

            // [n-tile][stream], AGPR
            f32x16 acc00 = (f32x16)(0.0f), acc01 = (f32x16)(0.0f), acc02 = (f32x16)(0.0f);
            f32x16 acc10 = (f32x16)(0.0f), acc11 = (f32x16)(0.0f), acc12 = (f32x16)(0.0f);

            // K-loop: wrap-around depth-2 A prefetch (L2 latency cover), B just-in-time.
            uint4 aC0 = Wp[abase];
            uint4 aC1 = Wp[abase + 64];
            uint4 aN0 = Wp[abase + 1024];
            uint4 aN1 = Wp[abase + 1024 + 64];
            #pragma unroll 2
            for (int c = 0; c < 32; ++c) {
                int i2 = abase + (((c + 2) & 31) << 10);
                uint4 aF0 = Wp[i2];
                uint4 aF1 = Wp[i2 + 64];
                int kx = (c << 5) | hi16;
                bf16x8 bf0 = __builtin_bit_cast(bf16x8, *(const uint4*)(xb + rowb0 + kx));
                bf16x8 bf1 = __builtin_bit_cast(bf16x8, *(const uint4*)(xb + rowb1 + kx));
                bf16x8 bf2 = __builtin_bit_cast(bf16x8, *(const uint4*)(xb + rowb2 + kx));
                bf16x8 av0 = __builtin_bit_cast(bf16x8, aC0);
                bf16x8 av1 = __builtin_bit_cast(bf16x8, aC1);
                __builtin_amdgcn_s_setprio(1);
                acc00 = __builtin_amdgcn_mfma_f32_32x32x16_bf16(av0, bf0, acc00, 0, 0, 0);
                acc10 = __builtin_amdgcn_mfma_f32_32x32x16_bf16(av1, bf0, acc10, 0, 0, 0);
                acc01 = __builtin_amdgcn_mfma_f32_32x32x16_bf16(av0, bf1, acc01, 0, 0, 0);
                acc11 = __builtin_amdgcn_mfma_f32_32x32x16_bf16(av1, bf1, acc11, 0, 0, 0);
                acc02 = __builtin_amdgcn_mfma_f32_32x32x16_bf16(av0, bf2, acc02, 0, 0, 0);
                acc12 = __builtin_amdgcn_mfma_f32_32x32x16_bf16(av1, bf2, acc12, 0, 0, 0);
                __builtin_amdgcn_s_setprio(0);
                aC0 = aN0; aC1 = aN1;
                aN0 = aF0; aN1 = aF1;
            }

            if (layer == 0) {
                __syncthreads();   // all waves done reading Xbuf before overwrite
                // epilogue 1: silu + JVP coupling; write next-layer X to LDS.
                // D col = sample = l31; D row n = n0w+nt*32+(reg&3)+8*(reg>>2)+4*hi
                char* pb = Xbuf + ROWB(l31);
                #pragma unroll
                for (int nt = 0; nt < 2; ++nt) {
                    const f32x16& a0r = nt ? acc10 : acc00;
                    const f32x16& a1r = nt ? acc11 : acc01;
                    const f32x16& a2r = nt ? acc12 : acc02;
                    #pragma unroll
                    for (int q = 0; q < 4; ++q) {
                        int nq = n0w + nt * 32 + 8 * q + 4 * hi;  // 4 consecutive n
                        f32x4 bq = *(const f32x4*)(bias + nq);
                        float hv[4], u0v[4], u1v[4];
                        #pragma unroll
                        for (int k = 0; k < 4; ++k) {
                            int reg = 4 * q + k;
                            float aa  = a0r[reg] + bq[k];
                            float sig = 1.0f / (1.0f + __expf(-aa));
                            float h   = aa * sig;
                            float sp  = fmaf(h, 1.0f - sig, sig);
                            hv[k]  = h;
                            u0v[k] = sp * a1r[reg];
                            u1v[k] = sp * a2r[reg];
                        }
                        int off = nq << 1;
                        uint2 vh = {pkbf2(hv[0],  hv[1]),  pkbf2(hv[2],  hv[3])};
                        uint2 v0 = {pkbf2(u0v[0], u0v[1]), pkbf2(u0v[2], u0v[3])};
                        uint2 v1 = {pkbf2(u1v[0], u1v[1]), pkbf2(u1v[2], u1v[3])};
                        *(uint2*)(pb + off)            = vh;
                        *(uint2*)(pb + ROWB(32) + off) = v0;
                        *(uint2*)(pb + ROWB(64) + off) = v1;
                    }
                }
                __syncthreads();
            } else {
                // epilogue 2: folded output projection (register-local W3 dots)
                float q0 = 0.f, q1 = 0.f, q2 = 0.f, q3 = 0.f, q4 = 0.f, q5 = 0.f;
                #pragma unroll
                for (int nt = 0; nt < 2; ++nt) {
                    const f32x16& a0r = nt ? acc10 : acc00;
                    const f32x16& a1r = nt ? acc11 : acc01;
                    const f32x16& a2r = nt ? acc12 : acc02;
                    #pragma unroll
                    for (int q = 0; q < 4; ++q) {
                        int nq = n0w + nt * 32 + 8 * q + 4 * hi;
                        f32x4 bq = *(const f32x4*)(bias + nq);
                        f32x4 w0 = *(const f32x4*)(W3 + nq);
                        f32x4 w1 = *(const f32x4*)(W3 + 512 + nq);
                        #pragma unroll
                        for (int k = 0; k < 4; ++k) {
                            int reg = 4 * q + k;
                            float aa  = a0r[reg] + bq[k];
                            float sig = 1.0f / (1.0f + __expf(-aa));
                            float h   = aa * sig;
                            float sp  = fmaf(h, 1.0f - sig, sig);
                            float u0  = sp * a1r[reg];
                            float u1  = sp * a2r[reg];
                            q0 = fmaf(w0[k], h,  q0);
                            q1 = fmaf(w1[k], h,  q1);
                            q2 = fmaf(w0[k], u0, q2);
                            q3 = fmaf(w1[k], u0, q3);
                            q4 = fmaf(w0[k], u1, q4);
                            q5 = fmaf(w1[k], u1, q5);
                        }
                    }
                }
                q0 += __shfl_xor(q0, 32);
                q1 += __shfl_xor(q1, 32);
                q2 += __shfl_xor(q2, 32);
                q3 += __shfl_xor(q3, 32);
                q4 += __shfl_xor(q4, 32);
                q5 += __shfl_xor(q5, 32);
                if (hi == 0) {
                    float* pp = &part[wid][l31][0];
                    pp[0] = q0; pp[1] = q1; pp[2] = q2;
                    pp[3] = q3; pp[4] = q4; pp[5] = q5;
                }
                __syncthreads();
            }
        }

        // ---------- state update: every thread sums 8 wave-partials (redundant,
        // deterministic) for its sample; z/log_det stay in registers ----------
        {
            float s0v = 0.f, s1v = 0.f, s2v = 0.f, s3v = 0.f, s4v = 0.f, s5v = 0.f;
            #pragma unroll
            for (int w = 0; w < 8; ++w) {
                const float* pp = &part[w][s0][0];
                s0v += pp[0]; s1v += pp[1]; s2v += pp[2];
                s3v += pp[3]; s4v += pp[4]; s5v += pp[5];
            }
            float v0 = s0v + b3x;
            float v1 = s1v + b3y;
            float det = (1.0f + 0.1f * s2v) * (1.0f + 0.1f * s5v)
                      - 0.01f * s4v * s3v;
            ldr += logf(fmaxf(fabsf(det), 1e-8f));
            z0r += 0.1f * v0;
            z1r += 0.1f * v1;
        }
        // no barrier: part re-written only after 3 barriers (next epi2);
        // next L0 writes Xbuf, whose readers all passed the part barrier.
    }

    if (t16 == 0) {
        out[wgs + s0] = -0.5f * (z0r * z0r + z1r * z1r) - 1.8378770664093453f + ldr;
    }
}

extern "C" void kernel_launch(void* const* d_in, const int* in_sizes, int n_in,
                              void* d_out, int out_size, void* d_ws, size_t ws_size,
                              hipStream_t stream) {
    const float* x  = (const float*)d_in[0];
    const float* W0 = (const float*)d_in[1];   // (512, 34)
    const float* b0 = (const float*)d_in[2];
    const float* W1 = (const float*)d_in[3];   // (512, 512)
    const float* b1 = (const float*)d_in[4];
    const float* W2 = (const float*)d_in[5];
    const float* b2 = (const float*)d_in[6];
    const float* W3 = (const float*)d_in[7];   // (2, 512)
    const float* b3 = (const float*)d_in[8];
    float* out = (float*)d_out;

    char* ws = (char*)d_ws;
    __hip_bfloat16* wpk1 = (__hip_bfloat16*)ws;                  // 512 KB
    __hip_bfloat16* wpk2 = (__hip_bfloat16*)(ws + (512u << 10)); // 512 KB
    float*          cstp = (float*)(ws + (1024u << 10));         // 20 KB
    float*          w01p = (float*)(ws + (1044u << 10));         // 4 KB

    pack_w_kernel<<<512, 512, 0, stream>>>(W1, wpk1);
    pack_w_kernel<<<512, 512, 0, stream>>>(W2, wpk2);
    cstep_kernel<<<10, 512, 0, stream>>>(W0, b0, cstp);
    pack_w0_kernel<<<1, 512, 0, stream>>>(W0, w01p);
    flow_kernel<<<131072 / 32, 512, 0, stream>>>(x, w01p, cstp, wpk1, wpk2,
                                                 b1, b2, W3, b3, out);
}

// Round 21
// 4988.016 us; speedup vs baseline: 1.0333x; 1.0333x over previous
//
#include <hip/hip_runtime.h>
#include <hip/hip_bf16.h>
#include <math.h>

// DiffusionFlow: fused 10-step flow + log-det on MI355X.
// Round 21 = r19 (4.95ms best) + ONLY the register-det fold from r20:
//  - det/state folded into registers: every thread redundantly sums the 8
//    wave-partials for its sample (identical fp order -> deterministic),
//    z/log_det live in registers. Removes det phase, zbuf/ldbuf, and one
//    barrier per step. part[8][32][9]: odd 9-float stride -> conflict-free.
//  - K-loop back to r19's depth-1 wrap-around A prefetch: r20's depth-2
//    added 16 v_movs + index VALU per iter in a VALU-saturated loop
//    (VALUBusy 43.8->45.3, MfmaUtil 38.9->36.5, dur +0.2ms). Reverted.

typedef float  f32x4  __attribute__((ext_vector_type(4)));
typedef float  f32x16 __attribute__((ext_vector_type(16)));
typedef __bf16 bf16x8 __attribute__((ext_vector_type(8)));

#define ROWB(r) (((r) << 10) + ((r) << 4))   // r * 1040

static __device__ __forceinline__ unsigned pkbf2(float a, float b) {
    unsigned short lo = __builtin_bit_cast(unsigned short, __float2bfloat16(a));
    unsigned short hi = __builtin_bit_cast(unsigned short, __float2bfloat16(b));
    return (unsigned)lo | ((unsigned)hi << 16);
}

// ---- pack W (512x512 row-major fp32) -> bf16 A-frag order for 32x32x16 ----
// out[(((c*16+nb)*64)+l)*8+j] = W[nb*32+(l&31)][c*16+(l>>5)*8+j]  (verified r5-r20)
__global__ void pack_w_kernel(const float* __restrict__ W,
                              __hip_bfloat16* __restrict__ out) {
    int i  = blockIdx.x * 512 + threadIdx.x;
    int c  = i >> 13;
    int nb = (i >> 9) & 15;
    int l  = (i >> 3) & 63;
    int j  = i & 7;
    int n  = nb * 32 + (l & 31);
    int k  = c * 16 + ((l >> 5) << 3) + j;
    out[i] = __float2bfloat16(W[n * 512 + k]);
}

// ---- pack W0 cols 0,1 -> contiguous [512][2] fp32 ----
__global__ void pack_w0_kernel(const float* __restrict__ W0,
                               float* __restrict__ w01) {
    int o = threadIdx.x;
    w01[o * 2 + 0] = W0[o * 34 + 0];
    w01[o * 2 + 1] = W0[o * 34 + 1];
}

// ---- c_step[k][o] = b0[o] + W0[o,2:34] . temb(t_k) ----
__global__ void cstep_kernel(const float* __restrict__ W0,
                             const float* __restrict__ b0,
                             float* __restrict__ cst) {
    int k = blockIdx.x;
    int o = threadIdx.x;
    float t = (float)k * 0.1f;
    float acc = b0[o];
    #pragma unroll
    for (int j = 0; j < 16; ++j) {
        float f   = expf(-9.210340371976184f * (float)j / 16.0f);
        float arg = t * f;
        acc += W0[o * 34 + 2 + j]  * sinf(arg);
        acc += W0[o * 34 + 18 + j] * cosf(arg);
    }
    cst[k * 512 + o] = acc;
}

__global__ __launch_bounds__(512)
void flow_kernel(const float* __restrict__ x,
                 const float* __restrict__ w01,
                 const float* __restrict__ cst,
                 const __hip_bfloat16* __restrict__ Wpk1,
                 const __hip_bfloat16* __restrict__ Wpk2,
                 const float* __restrict__ b1,
                 const float* __restrict__ b2,
                 const float* __restrict__ W3,
                 const float* __restrict__ b3v,
                 float* __restrict__ out)
{
    __shared__ __align__(16) char Xbuf[96 * 1040];           // 99.8 KB, odd stride
    __shared__ __align__(16) float part[8][32][9];           // 9-float stride: CF

    const int tid  = threadIdx.x;
    const int lane = tid & 63;
    const int wid  = tid >> 6;        // 0..7 -> cols [wid*64, wid*64+64)
    const int l31  = lane & 31;
    const int hi   = lane >> 5;       // 0/1
    const int n0w  = wid << 6;
    const int wgs  = blockIdx.x << 5; // 32 samples per WG

    // B-frag (X from LDS): rows l31 / 32+l31 / 64+l31, stride 1040
    const int rowb0 = ROWB(l31);
    const int rowb1 = ROWB(32 + l31);
    const int rowb2 = ROWB(64 + l31);
    const int hi16  = hi << 4;
    // A-frags: uint4 index = c*1024 + abase (+64 for 2nd n-tile)
    const int abase = (wid << 7) + lane;
    const uint4* Wp1 = (const uint4*)Wpk1;
    const uint4* Wp2 = (const uint4*)Wpk2;

    // L0 split: s0 = sample (tid>>4, 0..31), t16 = 16-way column split
    const int s0  = tid >> 4;
    const int t16 = tid & 15;

    // z / log_det in registers, redundant across the 16 threads of a sample
    float z0r = x[(wgs + s0) * 2 + 0];
    float z1r = x[(wgs + s0) * 2 + 1];
    float ldr = 0.0f;
    const float b3x = b3v[0];
    const float b3y = b3v[1];

    const char* xb = (const char*)Xbuf;

    #pragma unroll 1
    for (int step = 0; step < 10; ++step) {
        // ---------- layer 0: rank-2 + step-constant, 32 outs/thread ----------
        {
            const float* cs = cst + (step << 9);
            char* base0 = Xbuf + ROWB(s0);
            #pragma unroll 1
            for (int m = 0; m < 4; ++m) {
                int ob = (t16 << 5) + (m << 3);    // element base, 8 outs
                const float4* wv4 = (const float4*)(w01 + (ob << 1));
                const float4* cv4 = (const float4*)(cs + ob);
                unsigned ph[4], p0[4], p1[4];
                #pragma unroll
                for (int jj = 0; jj < 4; ++jj) {
                    float4 wv = wv4[jj];                    // pairs (x,y),(z,w)
                    float4 cv = cv4[jj >> 1];
                    float c0 = (jj & 1) ? cv.z : cv.x;
                    float c1 = (jj & 1) ? cv.w : cv.y;
                    float a0  = fmaf(z0r, wv.x, fmaf(z1r, wv.y, c0));
                    float sg0 = 1.0f / (1.0f + __expf(-a0));
                    float h0  = a0 * sg0;
                    float sp0 = fmaf(h0, 1.0f - sg0, sg0);  // silu'(a0)
                    float a1  = fmaf(z0r, wv.z, fmaf(z1r, wv.w, c1));
                    float sg1 = 1.0f / (1.0f + __expf(-a1));
                    float h1  = a1 * sg1;
                    float sp1 = fmaf(h1, 1.0f - sg1, sg1);
                    ph[jj] = pkbf2(h0, h1);
                    p0[jj] = pkbf2(sp0 * wv.x, sp1 * wv.z);
                    p1[jj] = pkbf2(sp0 * wv.y, sp1 * wv.w);
                }
                int off = ob << 1;
                uint4 vph = {ph[0], ph[1], ph[2], ph[3]};
                uint4 vp0 = {p0[0], p0[1], p0[2], p0[3]};
                uint4 vp1 = {p1[0], p1[1], p1[2], p1[3]};
                *(uint4*)(base0 + off)             = vph;
                *(uint4*)(base0 + ROWB(32) + off)  = vp0;
                *(uint4*)(base0 + ROWB(64) + off)  = vp1;
            }
        }
        __syncthreads();

        // ---------- layers 1,2: D = W @ X^T via 32x32x16 MFMA (intrinsic) ----------
        #pragma unroll 1
        for (int layer = 0; layer < 2; ++layer) {
            const uint4* __restrict__ Wp   = layer ? Wp2 : Wp1;
            const float* __restrict__ bias = layer ? b2  : b1;

            // [n-tile][stream], AGPR
            f32x16 acc00 = (f32x16)(0.0f), acc01 = (f32x16)(0.0f), acc02 = (f32x16)(0.0f);
            f32x16 acc10 = (f32x16)(0.0f), acc11 = (f32x16)(0.0f), acc12 = (f32x16)(0.0f);

            // minimal-live K-loop: wrap-around depth-1 A prefetch, B just-in-time.
            uint4 aCur0 = Wp[abase];
            uint4 aCur1 = Wp[abase + 64];
            #pragma unroll 2
            for (int c = 0; c < 32; ++c) {
                int nidx = abase + (((c + 1) & 31) << 10);
                uint4 aNxt0 = Wp[nidx];
                uint4 aNxt1 = Wp[nidx + 64];
                int kx = (c << 5) | hi16;
                bf16x8 bf0 = __builtin_bit_cast(bf16x8, *(const uint4*)(xb + rowb0 + kx));
                bf16x8 bf1 = __builtin_bit_cast(bf16x8, *(const uint4*)(xb + rowb1 + kx));
                bf16x8 bf2 = __builtin_bit_cast(bf16x8, *(const uint4*)(xb + rowb2 + kx));
                bf16x8 av0 = __builtin_bit_cast(bf16x8, aCur0);
                bf16x8 av1 = __builtin_bit_cast(bf16x8, aCur1);
                __builtin_amdgcn_s_setprio(1);
                acc00 = __builtin_amdgcn_mfma_f32_32x32x16_bf16(av0, bf0, acc00, 0, 0, 0);
                acc10 = __builtin_amdgcn_mfma_f32_32x32x16_bf16(av1, bf0, acc10, 0, 0, 0);
                acc01 = __builtin_amdgcn_mfma_f32_32x32x16_bf16(av0, bf1, acc01, 0, 0, 0);
                acc11 = __builtin_amdgcn_mfma_f32_32x32x16_bf16(av1, bf1, acc11, 0, 0, 0);
                acc02 = __builtin_amdgcn_mfma_f32_32x32x16_bf16(av0, bf2, acc02, 0, 0, 0);
                acc12 = __builtin_amdgcn_mfma_f32_32x32x16_bf16(av1, bf2, acc12, 0, 0, 0);
                __builtin_amdgcn_s_setprio(0);
                aCur0 = aNxt0;
                aCur1 = aNxt1;
            }

            if (layer == 0) {
                __syncthreads();   // all waves done reading Xbuf before overwrite
                // epilogue 1: silu + JVP coupling; write next-layer X to LDS.
                // D col = sample = l31; D row n = n0w+nt*32+(reg&3)+8*(reg>>2)+4*hi
                char* pb = Xbuf + ROWB(l31);
                #pragma unroll
                for (int nt = 0; nt < 2; ++nt) {
                    const f32x16& a0r = nt ? acc10 : acc00;
                    const f32x16& a1r = nt ? acc11 : acc01;
                    const f32x16& a2r = nt ? acc12 : acc02;
                    #pragma unroll
                    for (int q = 0; q < 4; ++q) {
                        int nq = n0w + nt * 32 + 8 * q + 4 * hi;  // 4 consecutive n
                        f32x4 bq = *(const f32x4*)(bias + nq);
                        float hv[4], u0v[4], u1v[4];
                        #pragma unroll
                        for (int k = 0; k < 4; ++k) {
                            int reg = 4 * q + k;
                            float aa  = a0r[reg] + bq[k];
                            float sig = 1.0f / (1.0f + __expf(-aa));
                            float h   = aa * sig;
                            float sp  = fmaf(h, 1.0f - sig, sig);
                            hv[k]  = h;
                            u0v[k] = sp * a1r[reg];
                            u1v[k] = sp * a2r[reg];
                        }
                        int off = nq << 1;
                        uint2 vh = {pkbf2(hv[0],  hv[1]),  pkbf2(hv[2],  hv[3])};
                        uint2 v0 = {pkbf2(u0v[0], u0v[1]), pkbf2(u0v[2], u0v[3])};
                        uint2 v1 = {pkbf2(u1v[0], u1v[1]), pkbf2(u1v[2], u1v[3])};
                        *(uint2*)(pb + off)            = vh;
                        *(uint2*)(pb + ROWB(32) + off) = v0;
                        *(uint2*)(pb + ROWB(64) + off) = v1;
                    }
                }
                __syncthreads();
            } else {
                // epilogue 2: folded output projection (register-local W3 dots)
                float q0 = 0.f, q1 = 0.f, q2 = 0.f, q3 = 0.f, q4 = 0.f, q5 = 0.f;
                #pragma unroll
                for (int nt = 0; nt < 2; ++nt) {
                    const f32x16& a0r = nt ? acc10 : acc00;
                    const f32x16& a1r = nt ? acc11 : acc01;
                    const f32x16& a2r = nt ? acc12 : acc02;
                    #pragma unroll
                    for (int q = 0; q < 4; ++q) {
                        int nq = n0w + nt * 32 + 8 * q + 4 * hi;
                        f32x4 bq = *(const f32x4*)(bias + nq);
                        f32x4 w0 = *(const f32x4*)(W3 + nq);
                        f32x4 w1 = *(const f32x4*)(W3 + 512 + nq);
                        #pragma unroll
                        for (int k = 0; k < 4; ++k) {
                            int reg = 4 * q + k;
                            float aa  = a0r[reg] + bq[k];
                            float sig = 1.0f / (1.0f + __expf(-aa));
                            float h   = aa * sig;
                            float sp  = fmaf(h, 1.0f - sig, sig);
                            float u0  = sp * a1r[reg];
                            float u1  = sp * a2r[reg];
                            q0 = fmaf(w0[k], h,  q0);
                            q1 = fmaf(w1[k], h,  q1);
                            q2 = fmaf(w0[k], u0, q2);
                            q3 = fmaf(w1[k], u0, q3);
                            q4 = fmaf(w0[k], u1, q4);
                            q5 = fmaf(w1[k], u1, q5);
                        }
                    }
                }
                q0 += __shfl_xor(q0, 32);
                q1 += __shfl_xor(q1, 32);
                q2 += __shfl_xor(q2, 32);
                q3 += __shfl_xor(q3, 32);
                q4 += __shfl_xor(q4, 32);
                q5 += __shfl_xor(q5, 32);
                if (hi == 0) {
                    float* pp = &part[wid][l31][0];
                    pp[0] = q0; pp[1] = q1; pp[2] = q2;
                    pp[3] = q3; pp[4] = q4; pp[5] = q5;
                }
                __syncthreads();
            }
        }

        // ---------- state update: every thread sums 8 wave-partials (redundant,
        // deterministic) for its sample; z/log_det stay in registers ----------
        {
            float s0v = 0.f, s1v = 0.f, s2v = 0.f, s3v = 0.f, s4v = 0.f, s5v = 0.f;
            #pragma unroll
            for (int w = 0; w < 8; ++w) {
                const float* pp = &part[w][s0][0];
                s0v += pp[0]; s1v += pp[1]; s2v += pp[2];
                s3v += pp[3]; s4v += pp[4]; s5v += pp[5];
            }
            float v0 = s0v + b3x;
            float v1 = s1v + b3y;
            float det = (1.0f + 0.1f * s2v) * (1.0f + 0.1f * s5v)
                      - 0.01f * s4v * s3v;
            ldr += logf(fmaxf(fabsf(det), 1e-8f));
            z0r += 0.1f * v0;
            z1r += 0.1f * v1;
        }
        // no barrier needed: part is re-written only after 3 barriers (next
        // epi2); next L0 writes Xbuf, whose readers all passed the part barrier.
    }

    if (t16 == 0) {
        out[wgs + s0] = -0.5f * (z0r * z0r + z1r * z1r) - 1.8378770664093453f + ldr;
    }
}

extern "C" void kernel_launch(void* const* d_in, const int* in_sizes, int n_in,
                              void* d_out, int out_size, void* d_ws, size_t ws_size,
                              hipStream_t stream) {
    const float* x  = (const float*)d_in[0];
    const float* W0 = (const float*)d_in[1];   // (512, 34)
    const float* b0 = (const float*)d_in[2];
    const float* W1 = (const float*)d_in[3];   // (512, 512)
    const float* b1 = (const float*)d_in[4];
    const float* W2 = (const float*)d_in[5];
    const float* b2 = (const float*)d_in[6];
    const float* W3 = (const float*)d_in[7];   // (2, 512)
    const float* b3 = (const float*)d_in[8];
    float* out = (float*)d_out;

    char* ws = (char*)d_ws;
    __hip_bfloat16* wpk1 = (__hip_bfloat16*)ws;                  // 512 KB
    __hip_bfloat16* wpk2 = (__hip_bfloat16*)(ws + (512u << 10)); // 512 KB
    float*          cstp = (float*)(ws + (1024u << 10));         // 20 KB
    float*          w01p = (float*)(ws + (1044u << 10));         // 4 KB

    pack_w_kernel<<<512, 512, 0, stream>>>(W1, wpk1);
    pack_w_kernel<<<512, 512, 0, stream>>>(W2, wpk2);
    cstep_kernel<<<10, 512, 0, stream>>>(W0, b0, cstp);
    pack_w0_kernel<<<1, 512, 0, stream>>>(W0, w01p);
    flow_kernel<<<131072 / 32, 512, 0, stream>>>(x, w01p, cstp, wpk1, wpk2,
                                                 b1, b2, W3, b3, out);
}